// Round 1
// baseline (1239.682 us; speedup 1.0000x reference)
//
#include <hip/hip_runtime.h>
#include <hip/hip_bf16.h>

#define S_LEN 2048
#define HID   3072
#define NH    16
#define NKV   8
#define HD    256
#define EPSV  1e-6f
#define SCALING 0.0625f
#define SOFTCAP 50.0f

typedef __attribute__((ext_vector_type(8))) short bf16x8;
typedef __attribute__((ext_vector_type(4))) float f32x4;

__device__ __forceinline__ unsigned short f2bf(float f) {
  union { float f; unsigned u; } x; x.f = f;
  unsigned r = x.u + 0x7FFFu + ((x.u >> 16) & 1u);   // RNE
  return (unsigned short)(r >> 16);
}

__device__ __forceinline__ void gload_lds16(const void* g, void* l) {
  __builtin_amdgcn_global_load_lds((const __attribute__((address_space(1))) void*)g,
                                   (__attribute__((address_space(3))) void*)l, 16, 0, 0);
}

// ---------------- f32 -> bf16 elementwise ----------------
__global__ __launch_bounds__(256) void conv_b(const float* __restrict__ in,
                                              unsigned short* __restrict__ out, int n) {
  int i = (blockIdx.x * 256 + threadIdx.x) * 4;
  if (i >= n) return;
  float4 v = *(const float4*)(in + i);
  ushort4 o;
  o.x = f2bf(v.x); o.y = f2bf(v.y); o.z = f2bf(v.z); o.w = f2bf(v.w);
  *(ushort4*)(out + i) = o;
}

// ---------------- f32 KxN -> bf16 NxK transpose-convert ----------------
__global__ __launch_bounds__(256) void conv_t(const float* __restrict__ W,
                                              unsigned short* __restrict__ WT,
                                              int K, int N) {
  __shared__ float tile[32][33];
  int tx = threadIdx.x & 31, ty = threadIdx.x >> 5;
  int n0 = blockIdx.x * 32, k0 = blockIdx.y * 32;
#pragma unroll
  for (int j = 0; j < 4; j++)
    tile[ty + j * 8][tx] = W[(size_t)(k0 + ty + j * 8) * N + n0 + tx];
  __syncthreads();
#pragma unroll
  for (int j = 0; j < 4; j++)
    WT[(size_t)(n0 + ty + j * 8) * K + k0 + tx] = f2bf(tile[tx][ty + j * 8]);
}

// ---------------- NT GEMM: A (MxK bf16) * B (NxK bf16) -> C (MxN) ----------------
// 128x128 tile, BK=32, 4 waves each 64x64, m97-style global_load_lds staging.
__global__ __launch_bounds__(256) void gemm_nt(const unsigned short* __restrict__ A,
                                               const unsigned short* __restrict__ B,
                                               float* __restrict__ Cf,
                                               unsigned short* __restrict__ Cb,
                                               int M, int N, int K, int write_bf16) {
  __shared__ unsigned short As[128 * 32];
  __shared__ unsigned short Bs[128 * 32];
  const int t = threadIdx.x;
  const int w = t >> 6, l = t & 63;
  const int m0 = blockIdx.y * 128, n0 = blockIdx.x * 128;
  const int wr = (w >> 1) * 64, wc = (w & 1) * 64;
  const int lr = l & 15, lk = (l >> 4) * 8;
  f32x4 acc[4][4] = {};

  const int e0 = t * 8;                 // linear element this thread stages (x2 insts)
  const int ar0 = e0 >> 5, ac0 = e0 & 31;
  const size_t abase = (size_t)(m0 + ar0) * K + ac0;
  const size_t bbase = (size_t)(n0 + ar0) * K + ac0;

  for (int k0 = 0; k0 < K; k0 += 32) {
    gload_lds16(A + abase + k0, As + e0);
    gload_lds16(A + abase + (size_t)64 * K + k0, As + e0 + 2048);
    gload_lds16(B + bbase + k0, Bs + e0);
    gload_lds16(B + bbase + (size_t)64 * K + k0, Bs + e0 + 2048);
    __syncthreads();
    bf16x8 af[4], bfv[4];
#pragma unroll
    for (int i = 0; i < 4; i++)
      af[i] = *(const bf16x8*)(As + (wr + i * 16 + lr) * 32 + lk);
#pragma unroll
    for (int i = 0; i < 4; i++)
      bfv[i] = *(const bf16x8*)(Bs + (wc + i * 16 + lr) * 32 + lk);
#pragma unroll
    for (int i = 0; i < 4; i++)
#pragma unroll
      for (int j = 0; j < 4; j++)
        acc[i][j] = __builtin_amdgcn_mfma_f32_16x16x32_bf16(af[i], bfv[j], acc[i][j], 0, 0, 0);
    __syncthreads();
  }

  const int rq = (l >> 4) * 4;
#pragma unroll
  for (int i = 0; i < 4; i++)
#pragma unroll
    for (int j = 0; j < 4; j++) {
      int mrow = m0 + wr + i * 16 + rq;
      int ncol = n0 + wc + j * 16 + lr;
      if (write_bf16) {
#pragma unroll
        for (int r = 0; r < 4; r++)
          Cb[(size_t)(mrow + r) * N + ncol] = f2bf(acc[i][j][r]);
      } else {
#pragma unroll
        for (int r = 0; r < 4; r++)
          Cf[(size_t)(mrow + r) * N + ncol] = acc[i][j][r];
      }
    }
}

// ---------------- fused RMSNorm + RoPE (one row of 256 per block) ----------------
__global__ __launch_bounds__(256) void norm_rope(const float* __restrict__ x,
                                                 unsigned short* __restrict__ out,
                                                 const float* __restrict__ w,
                                                 const float* __restrict__ fc,
                                                 const float* __restrict__ fs,
                                                 int heads_per_tok, float scale) {
  __shared__ float sh[256];
  __shared__ float red[4];
  int row = blockIdx.x;
  int t = threadIdx.x;
  float v = x[(size_t)row * 256 + t];
  float ss = v * v;
#pragma unroll
  for (int off = 32; off > 0; off >>= 1) ss += __shfl_down(ss, off);
  if ((t & 63) == 0) red[t >> 6] = ss;
  __syncthreads();
  float tot = red[0] + red[1] + red[2] + red[3];
  float rn = rsqrtf(tot * (1.0f / 256.0f) + EPSV);
  sh[t] = v * rn * (1.0f + w[t]);
  __syncthreads();
  if (t < 128) {
    int s = row / heads_per_tok;
    float xr = sh[t], xi = sh[t + 128];
    float c = fc[(size_t)s * 128 + t], sn = fs[(size_t)s * 128 + t];
    out[(size_t)row * 256 + t]       = f2bf((xr * c - xi * sn) * scale);
    out[(size_t)row * 256 + t + 128] = f2bf((xr * sn + xi * c) * scale);
  }
}

// ---------------- flash attention, softcap, causal ----------------
// grid (S/64, NH), 256 thr = 4 waves; wave w owns q rows [qbase+16w, +16).
__global__ __launch_bounds__(256) void attn(const unsigned short* __restrict__ Q,
                                            const unsigned short* __restrict__ Kc,
                                            const unsigned short* __restrict__ Vc,
                                            unsigned short* __restrict__ O) {
  __shared__ unsigned short Ks[32 * 264];   // keys row-major, pad 256->264 (bank spread)
  __shared__ unsigned short Vt[256 * 40];   // V transposed [d][key], pad 32->40
  __shared__ unsigned short Ps[4 * 16 * 40];
  const int t = threadIdx.x, w = t >> 6, l = t & 63;
  const int h = blockIdx.y, kvh = h >> 1;
  const int qbase = blockIdx.x * 64;
  const int lr = l & 15, lk = (l >> 4) * 8;
  const int wq0 = qbase + w * 16;

  bf16x8 qf[8];
#pragma unroll
  for (int c = 0; c < 8; c++)
    qf[c] = *(const bf16x8*)(Q + ((size_t)(wq0 + lr) * NH + h) * HD + c * 32 + lk);

  f32x4 o_acc[16] = {};
  float m_r[4] = {-1e30f, -1e30f, -1e30f, -1e30f};
  float l_r[4] = {0.f, 0.f, 0.f, 0.f};

  const int ntiles = (qbase + 64) >> 5;
  for (int tile = 0; tile < ntiles; tile++) {
    const int kv0 = tile << 5;
    __syncthreads();
#pragma unroll
    for (int i = 0; i < 4; i++) {
      int e = t * 8 + i * 2048;
      int row = e >> 8, col = e & 255;
      const size_t gb = ((size_t)(kv0 + row) * NKV + kvh) * HD + col;
      bf16x8 kvv = *(const bf16x8*)(Kc + gb);
      *(bf16x8*)(Ks + row * 264 + col) = kvv;
      bf16x8 vv = *(const bf16x8*)(Vc + gb);
#pragma unroll
      for (int j = 0; j < 8; j++)
        Vt[(col + j) * 40 + row] = (unsigned short)vv[j];
    }
    __syncthreads();
    if (kv0 > wq0 + 15) continue;   // wave-uniform: fully masked tile for this wave

    f32x4 sacc[2] = {};
#pragma unroll
    for (int c = 0; c < 8; c++) {
      bf16x8 k0f = *(const bf16x8*)(Ks + (0 + lr) * 264 + c * 32 + lk);
      bf16x8 k1f = *(const bf16x8*)(Ks + (16 + lr) * 264 + c * 32 + lk);
      sacc[0] = __builtin_amdgcn_mfma_f32_16x16x32_bf16(qf[c], k0f, sacc[0], 0, 0, 0);
      sacc[1] = __builtin_amdgcn_mfma_f32_16x16x32_bf16(qf[c], k1f, sacc[1], 0, 0, 0);
    }

    float p[2][4];
    float corr[4];
#pragma unroll
    for (int r = 0; r < 4; r++) {
      int qi = wq0 + (l >> 4) * 4 + r;
      float sv[2];
      float mx = -1e30f;
#pragma unroll
      for (int nb = 0; nb < 2; nb++) {
        int kj = kv0 + nb * 16 + lr;
        float sres = sacc[nb][r];
        float ax = fabsf(sres) * (2.0f / SOFTCAP);
        float e2 = __expf(-ax);
        float th = (1.f - e2) / (1.f + e2);
        sres = copysignf(th * SOFTCAP, sres);
        sv[nb] = (kj <= qi) ? sres : -1e30f;
        mx = fmaxf(mx, sv[nb]);
      }
#pragma unroll
      for (int off = 1; off < 16; off <<= 1) mx = fmaxf(mx, __shfl_xor(mx, off));
      float mnew = fmaxf(m_r[r], mx);
      corr[r] = __expf(m_r[r] - mnew);
      float rs = 0.f;
#pragma unroll
      for (int nb = 0; nb < 2; nb++) {
        int kj = kv0 + nb * 16 + lr;
        float pv = (kj <= qi) ? __expf(sv[nb] - mnew) : 0.f;
        p[nb][r] = pv;
        rs += pv;
      }
#pragma unroll
      for (int off = 1; off < 16; off <<= 1) rs += __shfl_xor(rs, off);
      l_r[r] = l_r[r] * corr[r] + rs;
      m_r[r] = mnew;
    }

    f32x4 c4;
    c4[0] = corr[0]; c4[1] = corr[1]; c4[2] = corr[2]; c4[3] = corr[3];
#pragma unroll
    for (int fn = 0; fn < 16; fn++) o_acc[fn] *= c4;
#pragma unroll
    for (int r = 0; r < 4; r++) {
      int q = (l >> 4) * 4 + r;
      Ps[w * 640 + q * 40 + lr]      = f2bf(p[0][r]);
      Ps[w * 640 + q * 40 + 16 + lr] = f2bf(p[1][r]);
    }
    bf16x8 pa = *(const bf16x8*)(Ps + w * 640 + lr * 40 + lk);
#pragma unroll
    for (int fn = 0; fn < 16; fn++) {
      bf16x8 vf = *(const bf16x8*)(Vt + (fn * 16 + lr) * 40 + lk);
      o_acc[fn] = __builtin_amdgcn_mfma_f32_16x16x32_bf16(pa, vf, o_acc[fn], 0, 0, 0);
    }
  }

  f32x4 inv4;
#pragma unroll
  for (int r = 0; r < 4; r++) inv4[r] = (l_r[r] > 0.f) ? 1.0f / l_r[r] : 0.f;
#pragma unroll
  for (int fn = 0; fn < 16; fn++) {
    f32x4 ov = o_acc[fn] * inv4;
#pragma unroll
    for (int r = 0; r < 4; r++) {
      int q = wq0 + (l >> 4) * 4 + r;
      O[((size_t)q * NH + h) * HD + fn * 16 + lr] = f2bf(ov[r]);
    }
  }
}

extern "C" void kernel_launch(void* const* d_in, const int* in_sizes, int n_in,
                              void* d_out, int out_size, void* d_ws, size_t ws_size,
                              hipStream_t stream) {
  const float* hidden = (const float*)d_in[0];
  const float* fc  = (const float*)d_in[1];
  const float* fs  = (const float*)d_in[2];
  const float* wq  = (const float*)d_in[7];
  const float* wk  = (const float*)d_in[8];
  const float* wv  = (const float*)d_in[9];
  const float* wo  = (const float*)d_in[10];
  const float* qnw = (const float*)d_in[11];
  const float* knw = (const float*)d_in[12];
  float* out = (float*)d_out;

  char* ws = (char*)d_ws;
  size_t off = 0;
  auto alloc = [&](size_t bytes) {
    char* p = ws + off;
    off += (bytes + 255) & ~(size_t)255;
    return p;
  };
  unsigned short* Xbf = (unsigned short*)alloc((size_t)S_LEN * HID * 2);
  unsigned short* WqT = (unsigned short*)alloc((size_t)4096 * HID * 2);
  unsigned short* WkT = (unsigned short*)alloc((size_t)2048 * HID * 2);
  unsigned short* WvT = (unsigned short*)alloc((size_t)2048 * HID * 2);
  unsigned short* WoT = (unsigned short*)alloc((size_t)HID * 4096 * 2);
  float* XQ32 = (float*)alloc((size_t)S_LEN * 4096 * 4);
  float* XK32 = (float*)alloc((size_t)S_LEN * 2048 * 4);
  unsigned short* Qbf = (unsigned short*)alloc((size_t)S_LEN * 4096 * 2);
  unsigned short* Kbf = (unsigned short*)alloc((size_t)S_LEN * 2048 * 2);
  unsigned short* Vbf = (unsigned short*)alloc((size_t)S_LEN * 2048 * 2);
  unsigned short* Obf = (unsigned short*)XQ32;   // alias: XQ32 dead after norm_rope

  conv_b<<<(S_LEN * HID) / 1024, 256, 0, stream>>>(hidden, Xbf, S_LEN * HID);
  conv_t<<<dim3(4096 / 32, HID / 32), 256, 0, stream>>>(wq, WqT, HID, 4096);
  conv_t<<<dim3(2048 / 32, HID / 32), 256, 0, stream>>>(wk, WkT, HID, 2048);
  conv_t<<<dim3(2048 / 32, HID / 32), 256, 0, stream>>>(wv, WvT, HID, 2048);
  conv_t<<<dim3(HID / 32, 4096 / 32), 256, 0, stream>>>(wo, WoT, 4096, HID);

  gemm_nt<<<dim3(4096 / 128, S_LEN / 128), 256, 0, stream>>>(Xbf, WqT, XQ32, nullptr, S_LEN, 4096, HID, 0);
  gemm_nt<<<dim3(2048 / 128, S_LEN / 128), 256, 0, stream>>>(Xbf, WkT, XK32, nullptr, S_LEN, 2048, HID, 0);
  gemm_nt<<<dim3(2048 / 128, S_LEN / 128), 256, 0, stream>>>(Xbf, WvT, nullptr, Vbf, S_LEN, 2048, HID, 1);

  norm_rope<<<S_LEN * NH, 256, 0, stream>>>(XQ32, Qbf, qnw, fc, fs, NH, SCALING);
  norm_rope<<<S_LEN * NKV, 256, 0, stream>>>(XK32, Kbf, knw, fc, fs, NKV, 1.0f);

  attn<<<dim3(S_LEN / 64, NH), 256, 0, stream>>>(Qbf, Kbf, Vbf, Obf);

  gemm_nt<<<dim3(HID / 128, S_LEN / 128), 256, 0, stream>>>(Obf, WoT, out, nullptr, S_LEN, HID, 4096, 0);
}

// Round 2
// 959.814 us; speedup vs baseline: 1.2916x; 1.2916x over previous
//
#include <hip/hip_runtime.h>
#include <hip/hip_bf16.h>

#define S_LEN 2048
#define HID   3072
#define NH    16
#define NKV   8
#define HD    256
#define EPSV  1e-6f
#define SCALING 0.0625f
#define SOFTCAP 50.0f

typedef __attribute__((ext_vector_type(8))) short bf16x8;
typedef __attribute__((ext_vector_type(4))) float f32x4;

__device__ __forceinline__ unsigned short f2bf(float f) {
  union { float f; unsigned u; } x; x.f = f;
  unsigned r = x.u + 0x7FFFu + ((x.u >> 16) & 1u);   // RNE
  return (unsigned short)(r >> 16);
}

__device__ __forceinline__ void gload_lds16(const void* g, void* l) {
  __builtin_amdgcn_global_load_lds((const __attribute__((address_space(1))) void*)g,
                                   (__attribute__((address_space(3))) void*)l, 16, 0, 0);
}

// ---------------- f32 -> bf16 elementwise ----------------
__global__ __launch_bounds__(256) void conv_b(const float* __restrict__ in,
                                              unsigned short* __restrict__ out, int n) {
  int i = (blockIdx.x * 256 + threadIdx.x) * 4;
  if (i >= n) return;
  float4 v = *(const float4*)(in + i);
  ushort4 o;
  o.x = f2bf(v.x); o.y = f2bf(v.y); o.z = f2bf(v.z); o.w = f2bf(v.w);
  *(ushort4*)(out + i) = o;
}

// ---------------- f32 KxN -> bf16 NxK transpose-convert ----------------
__global__ __launch_bounds__(256) void conv_t(const float* __restrict__ W,
                                              unsigned short* __restrict__ WT,
                                              int K, int N) {
  __shared__ float tile[32][33];
  int tx = threadIdx.x & 31, ty = threadIdx.x >> 5;
  int n0 = blockIdx.x * 32, k0 = blockIdx.y * 32;
#pragma unroll
  for (int j = 0; j < 4; j++)
    tile[ty + j * 8][tx] = W[(size_t)(k0 + ty + j * 8) * N + n0 + tx];
  __syncthreads();
#pragma unroll
  for (int j = 0; j < 4; j++)
    WT[(size_t)(n0 + ty + j * 8) * K + k0 + tx] = f2bf(tile[tx][ty + j * 8]);
}

// ---------------- bf16 RxC -> CxR transpose ----------------
__global__ __launch_bounds__(256) void tr_bf16(const unsigned short* __restrict__ in,
                                               unsigned short* __restrict__ out,
                                               int R, int C) {
  __shared__ unsigned short tile[32][33];
  int tx = threadIdx.x & 31, ty = threadIdx.x >> 5;
  int c0 = blockIdx.x * 32, r0 = blockIdx.y * 32;
#pragma unroll
  for (int j = 0; j < 4; j++)
    tile[ty + j * 8][tx] = in[(size_t)(r0 + ty + j * 8) * C + c0 + tx];
  __syncthreads();
#pragma unroll
  for (int j = 0; j < 4; j++)
    out[(size_t)(c0 + ty + j * 8) * R + r0 + tx] = tile[tx][ty + j * 8];
}

// ---------------- NT GEMM: A (MxK bf16) * B (NxK bf16) -> C (MxN) ----------------
__global__ __launch_bounds__(256) void gemm_nt(const unsigned short* __restrict__ A,
                                               const unsigned short* __restrict__ B,
                                               float* __restrict__ Cf,
                                               unsigned short* __restrict__ Cb,
                                               int M, int N, int K, int write_bf16) {
  __shared__ unsigned short As[128 * 32];
  __shared__ unsigned short Bs[128 * 32];
  const int t = threadIdx.x;
  const int w = t >> 6, l = t & 63;
  const int m0 = blockIdx.y * 128, n0 = blockIdx.x * 128;
  const int wr = (w >> 1) * 64, wc = (w & 1) * 64;
  const int lr = l & 15, lk = (l >> 4) * 8;
  f32x4 acc[4][4] = {};

  const int e0 = t * 8;
  const int ar0 = e0 >> 5, ac0 = e0 & 31;
  const size_t abase = (size_t)(m0 + ar0) * K + ac0;
  const size_t bbase = (size_t)(n0 + ar0) * K + ac0;

  for (int k0 = 0; k0 < K; k0 += 32) {
    gload_lds16(A + abase + k0, As + e0);
    gload_lds16(A + abase + (size_t)64 * K + k0, As + e0 + 2048);
    gload_lds16(B + bbase + k0, Bs + e0);
    gload_lds16(B + bbase + (size_t)64 * K + k0, Bs + e0 + 2048);
    __syncthreads();
    bf16x8 af[4], bfv[4];
#pragma unroll
    for (int i = 0; i < 4; i++)
      af[i] = *(const bf16x8*)(As + (wr + i * 16 + lr) * 32 + lk);
#pragma unroll
    for (int i = 0; i < 4; i++)
      bfv[i] = *(const bf16x8*)(Bs + (wc + i * 16 + lr) * 32 + lk);
#pragma unroll
    for (int i = 0; i < 4; i++)
#pragma unroll
      for (int j = 0; j < 4; j++)
        acc[i][j] = __builtin_amdgcn_mfma_f32_16x16x32_bf16(af[i], bfv[j], acc[i][j], 0, 0, 0);
    __syncthreads();
  }

  const int rq = (l >> 4) * 4;
#pragma unroll
  for (int i = 0; i < 4; i++)
#pragma unroll
    for (int j = 0; j < 4; j++) {
      int mrow = m0 + wr + i * 16 + rq;
      int ncol = n0 + wc + j * 16 + lr;
      if (write_bf16) {
#pragma unroll
        for (int r = 0; r < 4; r++)
          Cb[(size_t)(mrow + r) * N + ncol] = f2bf(acc[i][j][r]);
      } else {
#pragma unroll
        for (int r = 0; r < 4; r++)
          Cf[(size_t)(mrow + r) * N + ncol] = acc[i][j][r];
      }
    }
}

// ---------------- fused RMSNorm + RoPE; writes head-major [h][s][d] ----------------
__global__ __launch_bounds__(256) void norm_rope(const float* __restrict__ x,
                                                 unsigned short* __restrict__ out,
                                                 const float* __restrict__ w,
                                                 const float* __restrict__ fc,
                                                 const float* __restrict__ fs,
                                                 int heads_per_tok, float scale) {
  __shared__ float sh[256];
  __shared__ float red[4];
  int row = blockIdx.x;
  int t = threadIdx.x;
  float v = x[(size_t)row * 256 + t];
  float ss = v * v;
#pragma unroll
  for (int off = 32; off > 0; off >>= 1) ss += __shfl_down(ss, off);
  if ((t & 63) == 0) red[t >> 6] = ss;
  __syncthreads();
  float tot = red[0] + red[1] + red[2] + red[3];
  float rn = rsqrtf(tot * (1.0f / 256.0f) + EPSV);
  sh[t] = v * rn * (1.0f + w[t]);
  __syncthreads();
  if (t < 128) {
    int s = row / heads_per_tok;
    int h = row - s * heads_per_tok;
    size_t ob = ((size_t)h * S_LEN + s) * HD;
    float xr = sh[t], xi = sh[t + 128];
    float c = fc[(size_t)s * 128 + t], sn = fs[(size_t)s * 128 + t];
    out[ob + t]       = f2bf((xr * c - xi * sn) * scale);
    out[ob + t + 128] = f2bf((xr * sn + xi * c) * scale);
  }
}

// ---------------- flash attention, softcap, causal; no LDS staging ----------------
// Q: [NH][S][HD], K: [NKV][S][HD], VT: [NKV][HD][S], O: [S][NH*HD]
// 1D grid of 512 blocks; bid -> (kvh = bid&7 for XCD L2 locality, heavy q first)
__global__ __launch_bounds__(256) void attn(const unsigned short* __restrict__ Q,
                                            const unsigned short* __restrict__ Kc,
                                            const unsigned short* __restrict__ VT,
                                            unsigned short* __restrict__ O) {
  __shared__ unsigned short Ps[4][16][40];
  const int t = threadIdx.x, w = t >> 6, l = t & 63;
  const int n = blockIdx.x;
  const int kvh = n & 7;
  const int h = kvh * 2 + ((n >> 3) & 1);
  const int qbase = (31 - (n >> 4)) * 64;       // heavy tiles dispatched first
  const int lr = l & 15, g = l >> 4, lk = g * 8;
  const int wq0 = qbase + w * 16;

  const unsigned short* Qh = Q + (size_t)h * S_LEN * HD;
  const unsigned short* Kh = Kc + (size_t)kvh * S_LEN * HD;
  const unsigned short* Vh = VT + (size_t)kvh * HD * S_LEN;

  bf16x8 qf[8];
#pragma unroll
  for (int c = 0; c < 8; c++)
    qf[c] = *(const bf16x8*)(Qh + (size_t)(wq0 + lr) * HD + c * 32 + lk);

  f32x4 o_acc[16] = {};
  float m_r[4] = {-1e30f, -1e30f, -1e30f, -1e30f};
  float l_r[4] = {0.f, 0.f, 0.f, 0.f};

  const int ntw = (wq0 + 47) >> 5;              // tiles with kv0 <= wq0+15
  for (int tile = 0; tile < ntw; tile++) {
    const int kv0 = tile << 5;
    const bool masked = (kv0 + 31 > wq0);       // wave-uniform

    f32x4 sacc[2] = {};
#pragma unroll
    for (int c = 0; c < 8; c++) {
      bf16x8 k0f = *(const bf16x8*)(Kh + (size_t)(kv0 + lr) * HD + c * 32 + lk);
      bf16x8 k1f = *(const bf16x8*)(Kh + (size_t)(kv0 + 16 + lr) * HD + c * 32 + lk);
      sacc[0] = __builtin_amdgcn_mfma_f32_16x16x32_bf16(qf[c], k0f, sacc[0], 0, 0, 0);
      sacc[1] = __builtin_amdgcn_mfma_f32_16x16x32_bf16(qf[c], k1f, sacc[1], 0, 0, 0);
    }

    float p0a[4], p1a[4], corr[4];
#pragma unroll
    for (int r = 0; r < 4; r++) {
      float sv0 = sacc[0][r], sv1 = sacc[1][r];
      // softcap: tanh(s/50)*50
      {
        float ax = fabsf(sv0) * (2.0f / SOFTCAP);
        float e2 = __expf(-ax);
        sv0 = copysignf((1.f - e2) / (1.f + e2) * SOFTCAP, sv0);
        ax = fabsf(sv1) * (2.0f / SOFTCAP);
        e2 = __expf(-ax);
        sv1 = copysignf((1.f - e2) / (1.f + e2) * SOFTCAP, sv1);
      }
      if (masked) {
        int qi = wq0 + g * 4 + r;
        sv0 = (kv0 + lr <= qi) ? sv0 : -1e30f;
        sv1 = (kv0 + 16 + lr <= qi) ? sv1 : -1e30f;
      }
      float mx = fmaxf(sv0, sv1);
#pragma unroll
      for (int off = 1; off < 16; off <<= 1) mx = fmaxf(mx, __shfl_xor(mx, off));
      float mnew = fmaxf(m_r[r], mx);
      corr[r] = __expf(m_r[r] - mnew);
      float p0 = __expf(sv0 - mnew);
      float p1 = __expf(sv1 - mnew);
      p0a[r] = p0; p1a[r] = p1;
      float rs = p0 + p1;
#pragma unroll
      for (int off = 1; off < 16; off <<= 1) rs += __shfl_xor(rs, off);
      l_r[r] = l_r[r] * corr[r] + rs;
      m_r[r] = mnew;
    }

    // rescale O only when the max actually moved (bit-exact skip)
    bool need = (corr[0] + corr[1] + corr[2] + corr[3]) < 4.0f;
    if (__any(need)) {
      f32x4 c4;
      c4[0] = corr[0]; c4[1] = corr[1]; c4[2] = corr[2]; c4[3] = corr[3];
#pragma unroll
      for (int fn = 0; fn < 16; fn++) o_acc[fn] *= c4;
    }

#pragma unroll
    for (int r = 0; r < 4; r++) {
      int q = g * 4 + r;
      Ps[w][q][lr]      = f2bf(p0a[r]);
      Ps[w][q][16 + lr] = f2bf(p1a[r]);
    }
    bf16x8 pa = *(const bf16x8*)(&Ps[w][lr][lk]);
#pragma unroll
    for (int fn = 0; fn < 16; fn++) {
      bf16x8 vf = *(const bf16x8*)(Vh + (size_t)(fn * 16 + lr) * S_LEN + kv0 + lk);
      o_acc[fn] = __builtin_amdgcn_mfma_f32_16x16x32_bf16(pa, vf, o_acc[fn], 0, 0, 0);
    }
  }

  f32x4 inv4;
#pragma unroll
  for (int r = 0; r < 4; r++) inv4[r] = (l_r[r] > 0.f) ? 1.0f / l_r[r] : 0.f;
#pragma unroll
  for (int fn = 0; fn < 16; fn++) {
    f32x4 ov = o_acc[fn] * inv4;
#pragma unroll
    for (int r = 0; r < 4; r++) {
      int q = wq0 + g * 4 + r;
      O[(size_t)q * 4096 + h * HD + fn * 16 + lr] = f2bf(ov[r]);
    }
  }
}

extern "C" void kernel_launch(void* const* d_in, const int* in_sizes, int n_in,
                              void* d_out, int out_size, void* d_ws, size_t ws_size,
                              hipStream_t stream) {
  const float* hidden = (const float*)d_in[0];
  const float* fc  = (const float*)d_in[1];
  const float* fs  = (const float*)d_in[2];
  const float* wq  = (const float*)d_in[7];
  const float* wk  = (const float*)d_in[8];
  const float* wv  = (const float*)d_in[9];
  const float* wo  = (const float*)d_in[10];
  const float* qnw = (const float*)d_in[11];
  const float* knw = (const float*)d_in[12];
  float* out = (float*)d_out;

  char* ws = (char*)d_ws;
  size_t off = 0;
  auto alloc = [&](size_t bytes) {
    char* p = ws + off;
    off += (bytes + 255) & ~(size_t)255;
    return p;
  };
  unsigned short* Xbf = (unsigned short*)alloc((size_t)S_LEN * HID * 2);
  unsigned short* WqT = (unsigned short*)alloc((size_t)4096 * HID * 2);
  unsigned short* WkT = (unsigned short*)alloc((size_t)2048 * HID * 2);
  unsigned short* WvT = (unsigned short*)alloc((size_t)2048 * HID * 2);
  unsigned short* WoT = (unsigned short*)alloc((size_t)HID * 4096 * 2);
  float* XQ32 = (float*)alloc((size_t)S_LEN * 4096 * 4);
  float* XK32 = (float*)alloc((size_t)S_LEN * 2048 * 4);
  unsigned short* Qbf = (unsigned short*)alloc((size_t)S_LEN * 4096 * 2);
  unsigned short* Kbf = (unsigned short*)alloc((size_t)S_LEN * 2048 * 2);
  unsigned short* Vbf = (unsigned short*)alloc((size_t)S_LEN * 2048 * 2);
  unsigned short* Obf = (unsigned short*)XQ32;   // alias: XQ32 dead after norm_rope Q
  unsigned short* VTb = (unsigned short*)XK32;   // alias: XK32 dead after norm_rope K

  conv_b<<<(S_LEN * HID) / 1024, 256, 0, stream>>>(hidden, Xbf, S_LEN * HID);
  conv_t<<<dim3(4096 / 32, HID / 32), 256, 0, stream>>>(wq, WqT, HID, 4096);
  conv_t<<<dim3(2048 / 32, HID / 32), 256, 0, stream>>>(wk, WkT, HID, 2048);
  conv_t<<<dim3(2048 / 32, HID / 32), 256, 0, stream>>>(wv, WvT, HID, 2048);
  conv_t<<<dim3(HID / 32, 4096 / 32), 256, 0, stream>>>(wo, WoT, 4096, HID);

  gemm_nt<<<dim3(4096 / 128, S_LEN / 128), 256, 0, stream>>>(Xbf, WqT, XQ32, nullptr, S_LEN, 4096, HID, 0);
  gemm_nt<<<dim3(2048 / 128, S_LEN / 128), 256, 0, stream>>>(Xbf, WkT, XK32, nullptr, S_LEN, 2048, HID, 0);
  gemm_nt<<<dim3(2048 / 128, S_LEN / 128), 256, 0, stream>>>(Xbf, WvT, nullptr, Vbf, S_LEN, 2048, HID, 1);

  norm_rope<<<S_LEN * NH, 256, 0, stream>>>(XQ32, Qbf, qnw, fc, fs, NH, SCALING);
  norm_rope<<<S_LEN * NKV, 256, 0, stream>>>(XK32, Kbf, knw, fc, fs, NKV, 1.0f);

  tr_bf16<<<dim3(2048 / 32, 2048 / 32), 256, 0, stream>>>(Vbf, VTb, S_LEN, 2048);

  attn<<<512, 256, 0, stream>>>(Qbf, Kbf, VTb, Obf);

  gemm_nt<<<dim3(HID / 128, S_LEN / 128), 256, 0, stream>>>(Obf, WoT, out, nullptr, S_LEN, HID, 4096, 0);
}

// Round 3
// 726.948 us; speedup vs baseline: 1.7053x; 1.3203x over previous
//
#include <hip/hip_runtime.h>
#include <hip/hip_bf16.h>

#define S_LEN 2048
#define HID   3072
#define NH    16
#define NKV   8
#define HD    256
#define EPSV  1e-6f
#define SCALING 0.0625f
#define SOFTCAP 50.0f

typedef __attribute__((ext_vector_type(8))) short bf16x8;
typedef __attribute__((ext_vector_type(4))) float f32x4;

__device__ __forceinline__ unsigned short f2bf(float f) {
  union { float f; unsigned u; } x; x.f = f;
  unsigned r = x.u + 0x7FFFu + ((x.u >> 16) & 1u);   // RNE
  return (unsigned short)(r >> 16);
}

__device__ __forceinline__ void gload_lds16(const void* g, void* l) {
  __builtin_amdgcn_global_load_lds((const __attribute__((address_space(1))) void*)g,
                                   (__attribute__((address_space(3))) void*)l, 16, 0, 0);
}

// ---------------- f32 -> bf16 elementwise ----------------
__global__ __launch_bounds__(256) void conv_b(const float* __restrict__ in,
                                              unsigned short* __restrict__ out, int n) {
  int i = (blockIdx.x * 256 + threadIdx.x) * 4;
  if (i >= n) return;
  float4 v = *(const float4*)(in + i);
  ushort4 o;
  o.x = f2bf(v.x); o.y = f2bf(v.y); o.z = f2bf(v.z); o.w = f2bf(v.w);
  *(ushort4*)(out + i) = o;
}

// ---------------- f32 KxN -> bf16 NxK transpose-convert ----------------
__global__ __launch_bounds__(256) void conv_t(const float* __restrict__ W,
                                              unsigned short* __restrict__ WT,
                                              int K, int N) {
  __shared__ float tile[32][33];
  int tx = threadIdx.x & 31, ty = threadIdx.x >> 5;
  int n0 = blockIdx.x * 32, k0 = blockIdx.y * 32;
#pragma unroll
  for (int j = 0; j < 4; j++)
    tile[ty + j * 8][tx] = W[(size_t)(k0 + ty + j * 8) * N + n0 + tx];
  __syncthreads();
#pragma unroll
  for (int j = 0; j < 4; j++)
    WT[(size_t)(n0 + ty + j * 8) * K + k0 + tx] = f2bf(tile[tx][ty + j * 8]);
}

// ---------------- bf16 RxC -> CxR transpose ----------------
__global__ __launch_bounds__(256) void tr_bf16(const unsigned short* __restrict__ in,
                                               unsigned short* __restrict__ out,
                                               int R, int C) {
  __shared__ unsigned short tile[32][33];
  int tx = threadIdx.x & 31, ty = threadIdx.x >> 5;
  int c0 = blockIdx.x * 32, r0 = blockIdx.y * 32;
#pragma unroll
  for (int j = 0; j < 4; j++)
    tile[ty + j * 8][tx] = in[(size_t)(r0 + ty + j * 8) * C + c0 + tx];
  __syncthreads();
#pragma unroll
  for (int j = 0; j < 4; j++)
    out[(size_t)(c0 + ty + j * 8) * R + r0 + tx] = tile[tx][ty + j * 8];
}

// ---------------- fused QKV GEMM: X (2048x3072) * WqkvT (8192x3072) ----------------
// cols [0,4096) -> XQ f32 ; [4096,6144) -> XK f32 ; [6144,8192) -> V bf16
__global__ __launch_bounds__(256) void gemm_qkv(const unsigned short* __restrict__ A,
                                                const unsigned short* __restrict__ B,
                                                float* __restrict__ XQ,
                                                float* __restrict__ XK,
                                                unsigned short* __restrict__ Vb) {
  const int K = HID;
  __shared__ unsigned short As[128 * 32];
  __shared__ unsigned short Bs[128 * 32];
  const int t = threadIdx.x;
  const int w = t >> 6, l = t & 63;
  const int m0 = blockIdx.y * 128, n0 = blockIdx.x * 128;
  const int wr = (w >> 1) * 64, wc = (w & 1) * 64;
  const int lr = l & 15, lk = (l >> 4) * 8;
  f32x4 acc[4][4] = {};

  const int e0 = t * 8;
  const int ar0 = e0 >> 5, ac0 = e0 & 31;
  const size_t abase = (size_t)(m0 + ar0) * K + ac0;
  const size_t bbase = (size_t)(n0 + ar0) * K + ac0;

  for (int k0 = 0; k0 < K; k0 += 32) {
    gload_lds16(A + abase + k0, As + e0);
    gload_lds16(A + abase + (size_t)64 * K + k0, As + e0 + 2048);
    gload_lds16(B + bbase + k0, Bs + e0);
    gload_lds16(B + bbase + (size_t)64 * K + k0, Bs + e0 + 2048);
    __syncthreads();
    bf16x8 af[4], bfv[4];
#pragma unroll
    for (int i = 0; i < 4; i++)
      af[i] = *(const bf16x8*)(As + (wr + i * 16 + lr) * 32 + lk);
#pragma unroll
    for (int i = 0; i < 4; i++)
      bfv[i] = *(const bf16x8*)(Bs + (wc + i * 16 + lr) * 32 + lk);
#pragma unroll
    for (int i = 0; i < 4; i++)
#pragma unroll
      for (int j = 0; j < 4; j++)
        acc[i][j] = __builtin_amdgcn_mfma_f32_16x16x32_bf16(af[i], bfv[j], acc[i][j], 0, 0, 0);
    __syncthreads();
  }

  const int rq = (l >> 4) * 4;
#pragma unroll
  for (int i = 0; i < 4; i++)
#pragma unroll
    for (int j = 0; j < 4; j++) {
      int mrow = m0 + wr + i * 16 + rq;
      int ncol = n0 + wc + j * 16 + lr;
      if (ncol < 4096) {
#pragma unroll
        for (int r = 0; r < 4; r++)
          XQ[(size_t)(mrow + r) * 4096 + ncol] = acc[i][j][r];
      } else if (ncol < 6144) {
#pragma unroll
        for (int r = 0; r < 4; r++)
          XK[(size_t)(mrow + r) * 2048 + ncol - 4096] = acc[i][j][r];
      } else {
#pragma unroll
        for (int r = 0; r < 4; r++)
          Vb[(size_t)(mrow + r) * 2048 + ncol - 6144] = f2bf(acc[i][j][r]);
      }
    }
}

// ---------------- NT GEMM (out-proj): A (MxK) * B (NxK) -> C f32 ----------------
__global__ __launch_bounds__(256) void gemm_nt(const unsigned short* __restrict__ A,
                                               const unsigned short* __restrict__ B,
                                               float* __restrict__ Cf,
                                               int M, int N, int K) {
  __shared__ unsigned short As[128 * 32];
  __shared__ unsigned short Bs[128 * 32];
  const int t = threadIdx.x;
  const int w = t >> 6, l = t & 63;
  const int m0 = blockIdx.y * 128, n0 = blockIdx.x * 128;
  const int wr = (w >> 1) * 64, wc = (w & 1) * 64;
  const int lr = l & 15, lk = (l >> 4) * 8;
  f32x4 acc[4][4] = {};

  const int e0 = t * 8;
  const int ar0 = e0 >> 5, ac0 = e0 & 31;
  const size_t abase = (size_t)(m0 + ar0) * K + ac0;
  const size_t bbase = (size_t)(n0 + ar0) * K + ac0;

  for (int k0 = 0; k0 < K; k0 += 32) {
    gload_lds16(A + abase + k0, As + e0);
    gload_lds16(A + abase + (size_t)64 * K + k0, As + e0 + 2048);
    gload_lds16(B + bbase + k0, Bs + e0);
    gload_lds16(B + bbase + (size_t)64 * K + k0, Bs + e0 + 2048);
    __syncthreads();
    bf16x8 af[4], bfv[4];
#pragma unroll
    for (int i = 0; i < 4; i++)
      af[i] = *(const bf16x8*)(As + (wr + i * 16 + lr) * 32 + lk);
#pragma unroll
    for (int i = 0; i < 4; i++)
      bfv[i] = *(const bf16x8*)(Bs + (wc + i * 16 + lr) * 32 + lk);
#pragma unroll
    for (int i = 0; i < 4; i++)
#pragma unroll
      for (int j = 0; j < 4; j++)
        acc[i][j] = __builtin_amdgcn_mfma_f32_16x16x32_bf16(af[i], bfv[j], acc[i][j], 0, 0, 0);
    __syncthreads();
  }

  const int rq = (l >> 4) * 4;
#pragma unroll
  for (int i = 0; i < 4; i++)
#pragma unroll
    for (int j = 0; j < 4; j++) {
      int mrow = m0 + wr + i * 16 + rq;
      int ncol = n0 + wc + j * 16 + lr;
#pragma unroll
      for (int r = 0; r < 4; r++)
        Cf[(size_t)(mrow + r) * N + ncol] = acc[i][j][r];
    }
}

// ---------------- fused RMSNorm + RoPE; writes head-major [h][s][d] ----------------
__global__ __launch_bounds__(256) void norm_rope(const float* __restrict__ x,
                                                 unsigned short* __restrict__ out,
                                                 const float* __restrict__ w,
                                                 const float* __restrict__ fc,
                                                 const float* __restrict__ fs,
                                                 int heads_per_tok, float scale) {
  __shared__ float sh[256];
  __shared__ float red[4];
  int row = blockIdx.x;
  int t = threadIdx.x;
  float v = x[(size_t)row * 256 + t];
  float ss = v * v;
#pragma unroll
  for (int off = 32; off > 0; off >>= 1) ss += __shfl_down(ss, off);
  if ((t & 63) == 0) red[t >> 6] = ss;
  __syncthreads();
  float tot = red[0] + red[1] + red[2] + red[3];
  float rn = rsqrtf(tot * (1.0f / 256.0f) + EPSV);
  sh[t] = v * rn * (1.0f + w[t]);
  __syncthreads();
  if (t < 128) {
    int s = row / heads_per_tok;
    int h = row - s * heads_per_tok;
    size_t ob = ((size_t)h * S_LEN + s) * HD;
    float xr = sh[t], xi = sh[t + 128];
    float c = fc[(size_t)s * 128 + t], sn = fs[(size_t)s * 128 + t];
    out[ob + t]       = f2bf((xr * c - xi * sn) * scale);
    out[ob + t + 128] = f2bf((xr * sn + xi * c) * scale);
  }
}

// ---------------- flash attention: dbuf LDS staging, swizzled, softcap, causal ----
// Q: [NH][S][HD], K: [NKV][S][HD], VT: [NKV][HD][S], O: [S][NH*HD]
__global__ __launch_bounds__(256) void attn(const unsigned short* __restrict__ Q,
                                            const unsigned short* __restrict__ Kc,
                                            const unsigned short* __restrict__ VT,
                                            unsigned short* __restrict__ O) {
  __shared__ unsigned short Ks[2][32 * 256];   // [k][d], rows 512B, swz ((row&7)<<4)
  __shared__ unsigned short Vs[2][256 * 32];   // [d][k], rows 64B, swz (((row>>1)&3)<<4)
  __shared__ unsigned short Ps[4][16][40];
  const int t = threadIdx.x, w = t >> 6, l = t & 63;
  const int n = blockIdx.x;
  const int kvh = n & 7;
  const int h = kvh * 2 + ((n >> 3) & 1);
  const int qbase = (31 - (n >> 4)) * 64;       // heavy q-tiles dispatched first
  const int lr = l & 15, g = l >> 4, lk = g * 8;
  const int wq0 = qbase + w * 16;

  const unsigned short* Qh = Q + (size_t)h * S_LEN * HD;
  const char* Khb = (const char*)(Kc + (size_t)kvh * S_LEN * HD);
  const char* Vhb = (const char*)(VT + (size_t)kvh * HD * S_LEN);

  bf16x8 qf[8];
#pragma unroll
  for (int c = 0; c < 8; c++)
    qf[c] = *(const bf16x8*)(Qh + (size_t)(wq0 + lr) * HD + c * 32 + lk);

  f32x4 o_acc[16] = {};
  float m_r[4] = {-1e30f, -1e30f, -1e30f, -1e30f};
  float l_r[4] = {0.f, 0.f, 0.f, 0.f};

  // stage tile (32 keys) into buffer b: linear LDS dest, inverse-swizzled source
  auto stage = [&](int kv0, int b) {
#pragma unroll
    for (int i = 0; i < 4; i++) {
      int L = t * 16 + i * 4096;
      int ks = L ^ (((L >> 9) & 7) << 4);
      gload_lds16(Khb + (size_t)kv0 * 512 + ks, (char*)(Ks[b]) + L);
    }
#pragma unroll
    for (int i = 0; i < 4; i++) {
      int L = t * 16 + i * 4096;
      int d = L >> 6;
      int kb = (L & 63) ^ (((d >> 1) & 3) << 4);
      gload_lds16(Vhb + (size_t)d * (S_LEN * 2) + (size_t)kv0 * 2 + kb, (char*)(Vs[b]) + L);
    }
  };

  const int ntB = (qbase + 64) >> 5;
  stage(0, 0);
  __syncthreads();
  int buf = 0;
  for (int tile = 0; tile < ntB; tile++) {
    const int kv0 = tile << 5;
    if (tile + 1 < ntB) stage(kv0 + 32, buf ^ 1);

    if (kv0 <= wq0 + 15) {
      const bool masked = (kv0 + 31 > wq0);     // wave-uniform
      const char* Kb = (const char*)(Ks[buf]);
      const char* Vb = (const char*)(Vs[buf]);

      f32x4 sacc[2] = {};
#pragma unroll
      for (int c = 0; c < 8; c++) {
        int a0 = (lr * 512 + c * 64 + g * 16) ^ ((lr & 7) << 4);
        bf16x8 k0f = *(const bf16x8*)(Kb + a0);
        bf16x8 k1f = *(const bf16x8*)(Kb + a0 + 8192);   // row+16: same (row&7), +16*512B
        sacc[0] = __builtin_amdgcn_mfma_f32_16x16x32_bf16(qf[c], k0f, sacc[0], 0, 0, 0);
        sacc[1] = __builtin_amdgcn_mfma_f32_16x16x32_bf16(qf[c], k1f, sacc[1], 0, 0, 0);
      }

      float p0a[4], p1a[4], corr[4];
#pragma unroll
      for (int r = 0; r < 4; r++) {
        float sv0 = sacc[0][r], sv1 = sacc[1][r];
        {
          float ax = fabsf(sv0) * (2.0f / SOFTCAP);
          float e2 = __expf(-ax);
          sv0 = copysignf((1.f - e2) / (1.f + e2) * SOFTCAP, sv0);
          ax = fabsf(sv1) * (2.0f / SOFTCAP);
          e2 = __expf(-ax);
          sv1 = copysignf((1.f - e2) / (1.f + e2) * SOFTCAP, sv1);
        }
        if (masked) {
          int qi = wq0 + g * 4 + r;
          sv0 = (kv0 + lr <= qi) ? sv0 : -1e30f;
          sv1 = (kv0 + 16 + lr <= qi) ? sv1 : -1e30f;
        }
        float mx = fmaxf(sv0, sv1);
#pragma unroll
        for (int off = 1; off < 16; off <<= 1) mx = fmaxf(mx, __shfl_xor(mx, off));
        float mnew = fmaxf(m_r[r], mx);
        corr[r] = __expf(m_r[r] - mnew);
        float p0 = __expf(sv0 - mnew);
        float p1 = __expf(sv1 - mnew);
        p0a[r] = p0; p1a[r] = p1;
        float rs = p0 + p1;
#pragma unroll
        for (int off = 1; off < 16; off <<= 1) rs += __shfl_xor(rs, off);
        l_r[r] = l_r[r] * corr[r] + rs;
        m_r[r] = mnew;
      }

      bool need = (corr[0] + corr[1] + corr[2] + corr[3]) < 4.0f;
      if (__any(need)) {
        f32x4 c4;
        c4[0] = corr[0]; c4[1] = corr[1]; c4[2] = corr[2]; c4[3] = corr[3];
#pragma unroll
        for (int fn = 0; fn < 16; fn++) o_acc[fn] *= c4;
      }

#pragma unroll
      for (int r = 0; r < 4; r++) {
        int q = g * 4 + r;
        Ps[w][q][lr]      = f2bf(p0a[r]);
        Ps[w][q][16 + lr] = f2bf(p1a[r]);
      }
      bf16x8 pa = *(const bf16x8*)(&Ps[w][lr][lk]);
#pragma unroll
      for (int fn = 0; fn < 16; fn++) {
        int row = fn * 16 + lr;
        int av = (row * 64 + g * 16) ^ (((row >> 1) & 3) << 4);
        bf16x8 vf = *(const bf16x8*)(Vb + av);
        o_acc[fn] = __builtin_amdgcn_mfma_f32_16x16x32_bf16(pa, vf, o_acc[fn], 0, 0, 0);
      }
    }
    __syncthreads();
    buf ^= 1;
  }

  f32x4 inv4;
#pragma unroll
  for (int r = 0; r < 4; r++) inv4[r] = (l_r[r] > 0.f) ? 1.0f / l_r[r] : 0.f;
#pragma unroll
  for (int fn = 0; fn < 16; fn++) {
    f32x4 ov = o_acc[fn] * inv4;
#pragma unroll
    for (int r = 0; r < 4; r++) {
      int q = wq0 + g * 4 + r;
      O[(size_t)q * 4096 + h * HD + fn * 16 + lr] = f2bf(ov[r]);
    }
  }
}

extern "C" void kernel_launch(void* const* d_in, const int* in_sizes, int n_in,
                              void* d_out, int out_size, void* d_ws, size_t ws_size,
                              hipStream_t stream) {
  const float* hidden = (const float*)d_in[0];
  const float* fc  = (const float*)d_in[1];
  const float* fs  = (const float*)d_in[2];
  const float* wq  = (const float*)d_in[7];
  const float* wk  = (const float*)d_in[8];
  const float* wv  = (const float*)d_in[9];
  const float* wo  = (const float*)d_in[10];
  const float* qnw = (const float*)d_in[11];
  const float* knw = (const float*)d_in[12];
  float* out = (float*)d_out;

  char* ws = (char*)d_ws;
  size_t off = 0;
  auto alloc = [&](size_t bytes) {
    char* p = ws + off;
    off += (bytes + 255) & ~(size_t)255;
    return p;
  };
  unsigned short* Xbf    = (unsigned short*)alloc((size_t)S_LEN * HID * 2);
  unsigned short* WqkvT  = (unsigned short*)alloc((size_t)8192 * HID * 2);
  unsigned short* WoT    = (unsigned short*)alloc((size_t)HID * 4096 * 2);
  float*          XQ32   = (float*)alloc((size_t)S_LEN * 4096 * 4);
  float*          XK32   = (float*)alloc((size_t)S_LEN * 2048 * 4);
  unsigned short* Qbf    = (unsigned short*)alloc((size_t)S_LEN * 4096 * 2);
  unsigned short* Kbf    = (unsigned short*)alloc((size_t)S_LEN * 2048 * 2);
  unsigned short* Vbf    = (unsigned short*)alloc((size_t)S_LEN * 2048 * 2);
  unsigned short* Obf = (unsigned short*)XQ32;   // alias: XQ32 dead after norm_rope Q
  unsigned short* VTb = (unsigned short*)XK32;   // alias: XK32 dead after norm_rope K

  conv_b<<<(S_LEN * HID) / 1024, 256, 0, stream>>>(hidden, Xbf, S_LEN * HID);
  conv_t<<<dim3(4096 / 32, HID / 32), 256, 0, stream>>>(wq, WqkvT, HID, 4096);
  conv_t<<<dim3(2048 / 32, HID / 32), 256, 0, stream>>>(wk, WqkvT + (size_t)4096 * HID, HID, 2048);
  conv_t<<<dim3(2048 / 32, HID / 32), 256, 0, stream>>>(wv, WqkvT + (size_t)6144 * HID, HID, 2048);
  conv_t<<<dim3(HID / 32, 4096 / 32), 256, 0, stream>>>(wo, WoT, 4096, HID);

  gemm_qkv<<<dim3(8192 / 128, S_LEN / 128), 256, 0, stream>>>(Xbf, WqkvT, XQ32, XK32, Vbf);

  norm_rope<<<S_LEN * NH, 256, 0, stream>>>(XQ32, Qbf, qnw, fc, fs, NH, SCALING);
  norm_rope<<<S_LEN * NKV, 256, 0, stream>>>(XK32, Kbf, knw, fc, fs, NKV, 1.0f);

  tr_bf16<<<dim3(2048 / 32, 2048 / 32), 256, 0, stream>>>(Vbf, VTb, S_LEN, 2048);

  attn<<<512, 256, 0, stream>>>(Qbf, Kbf, VTb, Obf);

  gemm_nt<<<dim3(HID / 128, S_LEN / 128), 256, 0, stream>>>(Obf, WoT, out, S_LEN, HID, 4096);
}

// Round 4
// 681.180 us; speedup vs baseline: 1.8199x; 1.0672x over previous
//
#include <hip/hip_runtime.h>
#include <hip/hip_bf16.h>

#define S_LEN 2048
#define HID   3072
#define NH    16
#define NKV   8
#define HD    256
#define EPSV  1e-6f
#define SCALING 0.0625f
#define SOFTCAP 50.0f

typedef __attribute__((ext_vector_type(8))) short bf16x8;
typedef __attribute__((ext_vector_type(4))) float f32x4;

__device__ __forceinline__ unsigned short f2bf(float f) {
  union { float f; unsigned u; } x; x.f = f;
  unsigned r = x.u + 0x7FFFu + ((x.u >> 16) & 1u);   // RNE
  return (unsigned short)(r >> 16);
}

__device__ __forceinline__ void gload_lds16(const void* g, void* l) {
  __builtin_amdgcn_global_load_lds((const __attribute__((address_space(1))) void*)g,
                                   (__attribute__((address_space(3))) void*)l, 16, 0, 0);
}

// ---------------- f32 -> bf16 elementwise ----------------
__global__ __launch_bounds__(256) void conv_b(const float* __restrict__ in,
                                              unsigned short* __restrict__ out, int n) {
  int i = (blockIdx.x * 256 + threadIdx.x) * 4;
  if (i >= n) return;
  float4 v = *(const float4*)(in + i);
  ushort4 o;
  o.x = f2bf(v.x); o.y = f2bf(v.y); o.z = f2bf(v.z); o.w = f2bf(v.w);
  *(ushort4*)(out + i) = o;
}

// ---------------- f32 KxN -> bf16 NxK transpose-convert (64x64, vectorized) ----
__global__ __launch_bounds__(256) void conv_t(const float* __restrict__ W,
                                              unsigned short* __restrict__ WT,
                                              int K, int N) {
  __shared__ float tile[64][65];
  const int n0 = blockIdx.x * 64, k0 = blockIdx.y * 64;
  const int tr = threadIdx.x >> 4;      // 0..15
  const int tc = threadIdx.x & 15;      // 0..15
#pragma unroll
  for (int i = 0; i < 4; i++) {
    float4 v = *(const float4*)(W + (size_t)(k0 + tr + 16 * i) * N + n0 + tc * 4);
    tile[tr + 16 * i][tc * 4 + 0] = v.x;
    tile[tr + 16 * i][tc * 4 + 1] = v.y;
    tile[tr + 16 * i][tc * 4 + 2] = v.z;
    tile[tr + 16 * i][tc * 4 + 3] = v.w;
  }
  __syncthreads();
#pragma unroll
  for (int i = 0; i < 4; i++) {
    int nrow = tr + 16 * i;
    ushort4 o;
    o.x = f2bf(tile[tc * 4 + 0][nrow]);
    o.y = f2bf(tile[tc * 4 + 1][nrow]);
    o.z = f2bf(tile[tc * 4 + 2][nrow]);
    o.w = f2bf(tile[tc * 4 + 3][nrow]);
    *(ushort4*)(WT + (size_t)(n0 + nrow) * K + k0 + tc * 4) = o;
  }
}

// ---------------- bf16 RxC -> CxR transpose ----------------
__global__ __launch_bounds__(256) void tr_bf16(const unsigned short* __restrict__ in,
                                               unsigned short* __restrict__ out,
                                               int R, int C) {
  __shared__ unsigned short tile[32][33];
  int tx = threadIdx.x & 31, ty = threadIdx.x >> 5;
  int c0 = blockIdx.x * 32, r0 = blockIdx.y * 32;
#pragma unroll
  for (int j = 0; j < 4; j++)
    tile[ty + j * 8][tx] = in[(size_t)(r0 + ty + j * 8) * C + c0 + tx];
  __syncthreads();
#pragma unroll
  for (int j = 0; j < 4; j++)
    out[(size_t)(c0 + ty + j * 8) * R + r0 + tx] = tile[tx][ty + j * 8];
}

// ---------------- fused QKV GEMM: X (2048x3072) * WqkvT (8192x3072) ----------------
// cols [0,4096) -> XQ f32 ; [4096,6144) -> XK f32 ; [6144,8192) -> V bf16
// XCD remap: by-fastest within per-XCD bx-chunks (B panel stays L2-resident)
__global__ __launch_bounds__(256) void gemm_qkv(const unsigned short* __restrict__ A,
                                                const unsigned short* __restrict__ B,
                                                float* __restrict__ XQ,
                                                float* __restrict__ XK,
                                                unsigned short* __restrict__ Vb) {
  const int K = HID;
  __shared__ unsigned short As[128 * 32];
  __shared__ unsigned short Bs[128 * 32];
  const int t = threadIdx.x;
  const int w = t >> 6, l = t & 63;
  const int bid = blockIdx.y * gridDim.x + blockIdx.x;
  const int xcd = bid & 7, ii = bid >> 3;
  const int m0 = (ii & 15) * 128;                       // gridDim.y == 16
  const int n0 = (xcd * (gridDim.x >> 3) + (ii >> 4)) * 128;
  const int wr = (w >> 1) * 64, wc = (w & 1) * 64;
  const int lr = l & 15, lk = (l >> 4) * 8;
  f32x4 acc[4][4] = {};

  const int e0 = t * 8;
  const int ar0 = e0 >> 5, ac0 = e0 & 31;
  const size_t abase = (size_t)(m0 + ar0) * K + ac0;
  const size_t bbase = (size_t)(n0 + ar0) * K + ac0;

  for (int k0 = 0; k0 < K; k0 += 32) {
    gload_lds16(A + abase + k0, As + e0);
    gload_lds16(A + abase + (size_t)64 * K + k0, As + e0 + 2048);
    gload_lds16(B + bbase + k0, Bs + e0);
    gload_lds16(B + bbase + (size_t)64 * K + k0, Bs + e0 + 2048);
    __syncthreads();
    bf16x8 af[4], bfv[4];
#pragma unroll
    for (int i = 0; i < 4; i++)
      af[i] = *(const bf16x8*)(As + (wr + i * 16 + lr) * 32 + lk);
#pragma unroll
    for (int i = 0; i < 4; i++)
      bfv[i] = *(const bf16x8*)(Bs + (wc + i * 16 + lr) * 32 + lk);
#pragma unroll
    for (int i = 0; i < 4; i++)
#pragma unroll
      for (int j = 0; j < 4; j++)
        acc[i][j] = __builtin_amdgcn_mfma_f32_16x16x32_bf16(af[i], bfv[j], acc[i][j], 0, 0, 0);
    __syncthreads();
  }

  const int rq = (l >> 4) * 4;
#pragma unroll
  for (int i = 0; i < 4; i++)
#pragma unroll
    for (int j = 0; j < 4; j++) {
      int mrow = m0 + wr + i * 16 + rq;
      int ncol = n0 + wc + j * 16 + lr;
      if (ncol < 4096) {
#pragma unroll
        for (int r = 0; r < 4; r++)
          XQ[(size_t)(mrow + r) * 4096 + ncol] = acc[i][j][r];
      } else if (ncol < 6144) {
#pragma unroll
        for (int r = 0; r < 4; r++)
          XK[(size_t)(mrow + r) * 2048 + ncol - 4096] = acc[i][j][r];
      } else {
#pragma unroll
        for (int r = 0; r < 4; r++)
          Vb[(size_t)(mrow + r) * 2048 + ncol - 6144] = f2bf(acc[i][j][r]);
      }
    }
}

// ---------------- NT GEMM (out-proj): A (MxK) * B (NxK) -> C f32 ----------------
__global__ __launch_bounds__(256) void gemm_nt(const unsigned short* __restrict__ A,
                                               const unsigned short* __restrict__ B,
                                               float* __restrict__ Cf,
                                               int M, int N, int K) {
  __shared__ unsigned short As[128 * 32];
  __shared__ unsigned short Bs[128 * 32];
  const int t = threadIdx.x;
  const int w = t >> 6, l = t & 63;
  const int bid = blockIdx.y * gridDim.x + blockIdx.x;
  const int xcd = bid & 7, ii = bid >> 3;
  const int m0 = (ii & 15) * 128;                       // gridDim.y == 16
  const int n0 = (xcd * (gridDim.x >> 3) + (ii >> 4)) * 128;
  const int wr = (w >> 1) * 64, wc = (w & 1) * 64;
  const int lr = l & 15, lk = (l >> 4) * 8;
  f32x4 acc[4][4] = {};

  const int e0 = t * 8;
  const int ar0 = e0 >> 5, ac0 = e0 & 31;
  const size_t abase = (size_t)(m0 + ar0) * K + ac0;
  const size_t bbase = (size_t)(n0 + ar0) * K + ac0;

  for (int k0 = 0; k0 < K; k0 += 32) {
    gload_lds16(A + abase + k0, As + e0);
    gload_lds16(A + abase + (size_t)64 * K + k0, As + e0 + 2048);
    gload_lds16(B + bbase + k0, Bs + e0);
    gload_lds16(B + bbase + (size_t)64 * K + k0, Bs + e0 + 2048);
    __syncthreads();
    bf16x8 af[4], bfv[4];
#pragma unroll
    for (int i = 0; i < 4; i++)
      af[i] = *(const bf16x8*)(As + (wr + i * 16 + lr) * 32 + lk);
#pragma unroll
    for (int i = 0; i < 4; i++)
      bfv[i] = *(const bf16x8*)(Bs + (wc + i * 16 + lr) * 32 + lk);
#pragma unroll
    for (int i = 0; i < 4; i++)
#pragma unroll
      for (int j = 0; j < 4; j++)
        acc[i][j] = __builtin_amdgcn_mfma_f32_16x16x32_bf16(af[i], bfv[j], acc[i][j], 0, 0, 0);
    __syncthreads();
  }

  const int rq = (l >> 4) * 4;
#pragma unroll
  for (int i = 0; i < 4; i++)
#pragma unroll
    for (int j = 0; j < 4; j++) {
      int mrow = m0 + wr + i * 16 + rq;
      int ncol = n0 + wc + j * 16 + lr;
#pragma unroll
      for (int r = 0; r < 4; r++)
        Cf[(size_t)(mrow + r) * N + ncol] = acc[i][j][r];
    }
}

// ---------------- fused RMSNorm + RoPE; writes head-major [h][s][d] ----------------
__global__ __launch_bounds__(256) void norm_rope(const float* __restrict__ x,
                                                 unsigned short* __restrict__ out,
                                                 const float* __restrict__ w,
                                                 const float* __restrict__ fc,
                                                 const float* __restrict__ fs,
                                                 int heads_per_tok, float scale) {
  __shared__ float sh[256];
  __shared__ float red[4];
  int row = blockIdx.x;
  int t = threadIdx.x;
  float v = x[(size_t)row * 256 + t];
  float ss = v * v;
#pragma unroll
  for (int off = 32; off > 0; off >>= 1) ss += __shfl_down(ss, off);
  if ((t & 63) == 0) red[t >> 6] = ss;
  __syncthreads();
  float tot = red[0] + red[1] + red[2] + red[3];
  float rn = rsqrtf(tot * (1.0f / 256.0f) + EPSV);
  sh[t] = v * rn * (1.0f + w[t]);
  __syncthreads();
  if (t < 128) {
    int s = row / heads_per_tok;
    int h = row - s * heads_per_tok;
    size_t ob = ((size_t)h * S_LEN + s) * HD;
    float xr = sh[t], xi = sh[t + 128];
    float c = fc[(size_t)s * 128 + t], sn = fs[(size_t)s * 128 + t];
    out[ob + t]       = f2bf((xr * c - xi * sn) * scale);
    out[ob + t + 128] = f2bf((xr * sn + xi * c) * scale);
  }
}

// ---------------- flash attention: swapped-QK in-register softmax ----------------
// Q: [NH][S][HD], K: [NKV][S][HD], VT: [NKV][HD][S], O: [S][NH*HD]
// S^T = mfma(K,Q): lane owns q = wq0 + (l&15); 8 key-values in-register.
__global__ __launch_bounds__(256) void attn(const unsigned short* __restrict__ Q,
                                            const unsigned short* __restrict__ Kc,
                                            const unsigned short* __restrict__ VT,
                                            unsigned short* __restrict__ O) {
  __shared__ unsigned short Ks[2][32 * 256];   // [k][d], rows 512B, swz ((row&7)<<4)
  __shared__ unsigned short Vs[2][256 * 32];   // [d][k], rows 64B, swz (((row>>1)&3)<<4)
  __shared__ unsigned short Ps[4][16][40];     // [wave][q][key]
  const int t = threadIdx.x, w = t >> 6, l = t & 63;
  const int n = blockIdx.x;
  const int kvh = n & 7;
  const int h = kvh * 2 + ((n >> 3) & 1);
  const int qbase = (31 - (n >> 4)) * 64;       // heavy q-tiles dispatched first
  const int lr = l & 15, g = l >> 4, lk = g * 8;
  const int wq0 = qbase + w * 16;
  const int q_own = wq0 + lr;

  const unsigned short* Qh = Q + (size_t)h * S_LEN * HD;
  const char* Khb = (const char*)(Kc + (size_t)kvh * S_LEN * HD);
  const char* Vhb = (const char*)(VT + (size_t)kvh * HD * S_LEN);

  bf16x8 qf[8];
#pragma unroll
  for (int c = 0; c < 8; c++)
    qf[c] = *(const bf16x8*)(Qh + (size_t)(wq0 + lr) * HD + c * 32 + lk);

  f32x4 o_acc[16] = {};
  float m_s = -1e30f, l_s = 0.f;

  auto stage = [&](int kv0, int b) {
#pragma unroll
    for (int i = 0; i < 4; i++) {
      int L = t * 16 + i * 4096;
      int ks = L ^ (((L >> 9) & 7) << 4);
      gload_lds16(Khb + (size_t)kv0 * 512 + ks, (char*)(Ks[b]) + L);
    }
#pragma unroll
    for (int i = 0; i < 4; i++) {
      int L = t * 16 + i * 4096;
      int d = L >> 6;
      int kb = (L & 63) ^ (((d >> 1) & 3) << 4);
      gload_lds16(Vhb + (size_t)d * (S_LEN * 2) + (size_t)kv0 * 2 + kb, (char*)(Vs[b]) + L);
    }
  };

  const int ntB = (qbase + 64) >> 5;
  stage(0, 0);
  __syncthreads();
  int buf = 0;
  for (int tile = 0; tile < ntB; tile++) {
    const int kv0 = tile << 5;
    if (tile + 1 < ntB) stage(kv0 + 32, buf ^ 1);

    if (kv0 <= wq0 + 15) {
      const bool masked = (kv0 + 31 > wq0);     // wave-uniform
      const char* Kb = (const char*)(Ks[buf]);
      const char* Vb = (const char*)(Vs[buf]);

      // S^T: rows=keys, cols=q
      f32x4 sacc[2] = {};
#pragma unroll
      for (int c = 0; c < 8; c++) {
        int a0 = (lr * 512 + c * 64 + g * 16) ^ ((lr & 7) << 4);
        bf16x8 k0f = *(const bf16x8*)(Kb + a0);
        bf16x8 k1f = *(const bf16x8*)(Kb + a0 + 8192);
        sacc[0] = __builtin_amdgcn_mfma_f32_16x16x32_bf16(k0f, qf[c], sacc[0], 0, 0, 0);
        sacc[1] = __builtin_amdgcn_mfma_f32_16x16x32_bf16(k1f, qf[c], sacc[1], 0, 0, 0);
      }

      // softcap + mask, all in-register (lane: q=q_own, keys kv0 + nb*16 + 4g + r)
      float sv[8];
#pragma unroll
      for (int nb = 0; nb < 2; nb++)
#pragma unroll
        for (int r = 0; r < 4; r++) {
          float s = sacc[nb][r];
          float ax = fabsf(s) * (2.0f / SOFTCAP);
          float e2 = __expf(-ax);
          s = copysignf((1.f - e2) / (1.f + e2) * SOFTCAP, s);
          if (masked) {
            int kj = kv0 + nb * 16 + 4 * g + r;
            s = (kj <= q_own) ? s : -1e30f;
          }
          sv[nb * 4 + r] = s;
        }

      float mx = fmaxf(fmaxf(fmaxf(sv[0], sv[1]), fmaxf(sv[2], sv[3])),
                       fmaxf(fmaxf(sv[4], sv[5]), fmaxf(sv[6], sv[7])));
      mx = fmaxf(mx, __shfl_xor(mx, 16));
      mx = fmaxf(mx, __shfl_xor(mx, 32));
      float mnew = fmaxf(m_s, mx);
      float corr = __expf(m_s - mnew);

      float ps[8];
      float rs = 0.f;
#pragma unroll
      for (int i = 0; i < 8; i++) {
        ps[i] = __expf(sv[i] - mnew);
        rs += ps[i];
      }
      rs += __shfl_xor(rs, 16);
      rs += __shfl_xor(rs, 32);
      l_s = l_s * corr + rs;
      m_s = mnew;

      if (__any(corr < 1.0f)) {
        f32x4 c4;
#pragma unroll
        for (int r = 0; r < 4; r++) c4[r] = __shfl(corr, 4 * g + r);
#pragma unroll
        for (int fn = 0; fn < 16; fn++) o_acc[fn] *= c4;
      }

      // pack P -> bf16 pairs, 2x ds_write_b64 at [q][4g], [q][16+4g]
      uint2 lo, hi;
      lo.x = (unsigned)f2bf(ps[0]) | ((unsigned)f2bf(ps[1]) << 16);
      lo.y = (unsigned)f2bf(ps[2]) | ((unsigned)f2bf(ps[3]) << 16);
      hi.x = (unsigned)f2bf(ps[4]) | ((unsigned)f2bf(ps[5]) << 16);
      hi.y = (unsigned)f2bf(ps[6]) | ((unsigned)f2bf(ps[7]) << 16);
      *(uint2*)(&Ps[w][lr][4 * g])      = lo;
      *(uint2*)(&Ps[w][lr][16 + 4 * g]) = hi;

      bf16x8 pa = *(const bf16x8*)(&Ps[w][lr][8 * g]);
#pragma unroll
      for (int fn = 0; fn < 16; fn++) {
        int row = fn * 16 + lr;
        int av = (row * 64 + g * 16) ^ (((row >> 1) & 3) << 4);
        bf16x8 vf = *(const bf16x8*)(Vb + av);
        o_acc[fn] = __builtin_amdgcn_mfma_f32_16x16x32_bf16(pa, vf, o_acc[fn], 0, 0, 0);
      }
    }
    __syncthreads();
    buf ^= 1;
  }

  float inv = (l_s > 0.f) ? 1.0f / l_s : 0.f;
  f32x4 inv4;
#pragma unroll
  for (int r = 0; r < 4; r++) inv4[r] = __shfl(inv, 4 * g + r);
#pragma unroll
  for (int fn = 0; fn < 16; fn++) {
    f32x4 ov = o_acc[fn] * inv4;
#pragma unroll
    for (int r = 0; r < 4; r++) {
      int q = wq0 + g * 4 + r;
      O[(size_t)q * 4096 + h * HD + fn * 16 + lr] = f2bf(ov[r]);
    }
  }
}

extern "C" void kernel_launch(void* const* d_in, const int* in_sizes, int n_in,
                              void* d_out, int out_size, void* d_ws, size_t ws_size,
                              hipStream_t stream) {
  const float* hidden = (const float*)d_in[0];
  const float* fc  = (const float*)d_in[1];
  const float* fs  = (const float*)d_in[2];
  const float* wq  = (const float*)d_in[7];
  const float* wk  = (const float*)d_in[8];
  const float* wv  = (const float*)d_in[9];
  const float* wo  = (const float*)d_in[10];
  const float* qnw = (const float*)d_in[11];
  const float* knw = (const float*)d_in[12];
  float* out = (float*)d_out;

  char* ws = (char*)d_ws;
  size_t off = 0;
  auto alloc = [&](size_t bytes) {
    char* p = ws + off;
    off += (bytes + 255) & ~(size_t)255;
    return p;
  };
  unsigned short* Xbf    = (unsigned short*)alloc((size_t)S_LEN * HID * 2);
  unsigned short* WqkvT  = (unsigned short*)alloc((size_t)8192 * HID * 2);
  unsigned short* WoT    = (unsigned short*)alloc((size_t)HID * 4096 * 2);
  float*          XQ32   = (float*)alloc((size_t)S_LEN * 4096 * 4);
  float*          XK32   = (float*)alloc((size_t)S_LEN * 2048 * 4);
  unsigned short* Qbf    = (unsigned short*)alloc((size_t)S_LEN * 4096 * 2);
  unsigned short* Kbf    = (unsigned short*)alloc((size_t)S_LEN * 2048 * 2);
  unsigned short* Vbf    = (unsigned short*)alloc((size_t)S_LEN * 2048 * 2);
  unsigned short* Obf = (unsigned short*)XQ32;   // alias: XQ32 dead after norm_rope Q
  unsigned short* VTb = (unsigned short*)XK32;   // alias: XK32 dead after norm_rope K

  conv_b<<<(S_LEN * HID) / 1024, 256, 0, stream>>>(hidden, Xbf, S_LEN * HID);
  conv_t<<<dim3(4096 / 64, HID / 64), 256, 0, stream>>>(wq, WqkvT, HID, 4096);
  conv_t<<<dim3(2048 / 64, HID / 64), 256, 0, stream>>>(wk, WqkvT + (size_t)4096 * HID, HID, 2048);
  conv_t<<<dim3(2048 / 64, HID / 64), 256, 0, stream>>>(wv, WqkvT + (size_t)6144 * HID, HID, 2048);
  conv_t<<<dim3(HID / 64, 4096 / 64), 256, 0, stream>>>(wo, WoT, 4096, HID);

  gemm_qkv<<<dim3(8192 / 128, S_LEN / 128), 256, 0, stream>>>(Xbf, WqkvT, XQ32, XK32, Vbf);

  norm_rope<<<S_LEN * NH, 256, 0, stream>>>(XQ32, Qbf, qnw, fc, fs, NH, SCALING);
  norm_rope<<<S_LEN * NKV, 256, 0, stream>>>(XK32, Kbf, knw, fc, fs, NKV, 1.0f);

  tr_bf16<<<dim3(2048 / 32, 2048 / 32), 256, 0, stream>>>(Vbf, VTb, S_LEN, 2048);

  attn<<<512, 256, 0, stream>>>(Qbf, Kbf, VTb, Obf);

  gemm_nt<<<dim3(HID / 128, S_LEN / 128), 256, 0, stream>>>(Obf, WoT, out, S_LEN, HID, 4096);
}

// Round 6
// 624.103 us; speedup vs baseline: 1.9863x; 1.0915x over previous
//
#include <hip/hip_runtime.h>
#include <hip/hip_bf16.h>

#define S_LEN 2048
#define HID   3072
#define NH    16
#define NKV   8
#define HD    256
#define EPSV  1e-6f
#define SCALING 0.0625f
#define SOFTCAP 50.0f

typedef __attribute__((ext_vector_type(8))) short bf16x8;
typedef __attribute__((ext_vector_type(4))) float f32x4;

__device__ __forceinline__ unsigned short f2bf(float f) {
  union { float f; unsigned u; } x; x.f = f;
  unsigned r = x.u + 0x7FFFu + ((x.u >> 16) & 1u);   // RNE
  return (unsigned short)(r >> 16);
}

__device__ __forceinline__ void gload_lds16(const void* g, void* l) {
  __builtin_amdgcn_global_load_lds((const __attribute__((address_space(1))) void*)g,
                                   (__attribute__((address_space(3))) void*)l, 16, 0, 0);
}

// ---------------- f32 -> bf16 elementwise ----------------
__global__ __launch_bounds__(256) void conv_b(const float* __restrict__ in,
                                              unsigned short* __restrict__ out, int n) {
  int i = (blockIdx.x * 256 + threadIdx.x) * 4;
  if (i >= n) return;
  float4 v = *(const float4*)(in + i);
  ushort4 o;
  o.x = f2bf(v.x); o.y = f2bf(v.y); o.z = f2bf(v.z); o.w = f2bf(v.w);
  *(ushort4*)(out + i) = o;
}

// ---------------- f32 KxN -> bf16 NxK transpose-convert (64x64, vectorized) ----
__global__ __launch_bounds__(256) void conv_t(const float* __restrict__ W,
                                              unsigned short* __restrict__ WT,
                                              int K, int N) {
  __shared__ float tile[64][65];
  const int n0 = blockIdx.x * 64, k0 = blockIdx.y * 64;
  const int tr = threadIdx.x >> 4;      // 0..15
  const int tc = threadIdx.x & 15;      // 0..15
#pragma unroll
  for (int i = 0; i < 4; i++) {
    float4 v = *(const float4*)(W + (size_t)(k0 + tr + 16 * i) * N + n0 + tc * 4);
    tile[tr + 16 * i][tc * 4 + 0] = v.x;
    tile[tr + 16 * i][tc * 4 + 1] = v.y;
    tile[tr + 16 * i][tc * 4 + 2] = v.z;
    tile[tr + 16 * i][tc * 4 + 3] = v.w;
  }
  __syncthreads();
#pragma unroll
  for (int i = 0; i < 4; i++) {
    int nrow = tr + 16 * i;
    ushort4 o;
    o.x = f2bf(tile[tc * 4 + 0][nrow]);
    o.y = f2bf(tile[tc * 4 + 1][nrow]);
    o.z = f2bf(tile[tc * 4 + 2][nrow]);
    o.w = f2bf(tile[tc * 4 + 3][nrow]);
    *(ushort4*)(WT + (size_t)(n0 + nrow) * K + k0 + tc * 4) = o;
  }
}

// ---------------- bf16 RxC -> CxR transpose ----------------
__global__ __launch_bounds__(256) void tr_bf16(const unsigned short* __restrict__ in,
                                               unsigned short* __restrict__ out,
                                               int R, int C) {
  __shared__ unsigned short tile[32][33];
  int tx = threadIdx.x & 31, ty = threadIdx.x >> 5;
  int c0 = blockIdx.x * 32, r0 = blockIdx.y * 32;
#pragma unroll
  for (int j = 0; j < 4; j++)
    tile[ty + j * 8][tx] = in[(size_t)(r0 + ty + j * 8) * C + c0 + tx];
  __syncthreads();
#pragma unroll
  for (int j = 0; j < 4; j++)
    out[(size_t)(c0 + ty + j * 8) * R + r0 + tx] = tile[tx][ty + j * 8];
}

// ---------------- fused QKV GEMM, 256x256 tile, BK=64, 8 waves, dbuf+swizzle ----
// X (2048x3072 bf16) * WqkvT (8192x3072 bf16, NxK).
// cols [0,4096) -> XQ f32 ; [4096,6144) -> XK f32 ; [6144,8192) -> V bf16
// Grid: 256 blocks (1/CU). bid&7 = XCD owns n-cols [xcd*4, xcd*4+4).
__global__ __launch_bounds__(512, 2) void gemm_qkv(const unsigned short* __restrict__ A,
                                                   const unsigned short* __restrict__ B,
                                                   float* __restrict__ XQ,
                                                   float* __restrict__ XK,
                                                   unsigned short* __restrict__ Vb) {
  const int K = HID;
  extern __shared__ char smem[];
  char* As0 = smem;                 // [2][32768] bytes (256 rows x 128 B)
  char* Bs0 = smem + 65536;         // [2][32768] bytes

  const int t = threadIdx.x;
  const int w = t >> 6, l = t & 63;
  const int lr = l & 15, g = l >> 4;      // frag row / k-slot group
  const int wr = w >> 2, wc = w & 3;      // 2 x 4 wave grid
  const int bid = blockIdx.x;
  const int xcd = bid & 7, ii = bid >> 3;
  const int m0 = (ii & 7) * 256;
  const int n0 = (xcd * 4 + (ii >> 3)) * 256;

  const char* Ab = (const char*)A;
  const char* Bb = (const char*)B;
  const int rowbytes = K * 2;

  f32x4 acc[8][4] = {};

  // stage K-tile [k0, k0+64) into buffer b: linear LDS dest, pre-swizzled source
  auto stage = [&](int k0, int b) {
#pragma unroll
    for (int i = 0; i < 4; i++) {
      int L = t * 16 + i * 8192;
      int r = L >> 7;
      int colB = (L & 127) ^ ((r & 7) << 4);
      gload_lds16(Ab + (size_t)(m0 + r) * rowbytes + k0 * 2 + colB, As0 + b * 32768 + L);
    }
#pragma unroll
    for (int i = 0; i < 4; i++) {
      int L = t * 16 + i * 8192;
      int r = L >> 7;
      int colB = (L & 127) ^ ((r & 7) << 4);
      gload_lds16(Bb + (size_t)(n0 + r) * rowbytes + k0 * 2 + colB, Bs0 + b * 32768 + L);
    }
  };

  const int swz = (lr & 7) << 4;
  const int NT = K / 64;            // 48
  stage(0, 0);
  for (int T = 0; T < NT; T++) {
    __syncthreads();                // tile T resident (loads are ~1 iter old)
    if (T + 1 < NT) stage((T + 1) * 64, (T + 1) & 1);
    const char* Ap = As0 + (T & 1) * 32768;
    const char* Bp = Bs0 + (T & 1) * 32768;
#pragma unroll
    for (int ks = 0; ks < 2; ks++) {
      bf16x8 af[8], bfv[4];
#pragma unroll
      for (int i = 0; i < 8; i++) {
        int row = wr * 128 + i * 16 + lr;
        af[i] = *(const bf16x8*)(Ap + ((row * 128 + ks * 64 + g * 16) ^ swz));
      }
#pragma unroll
      for (int j = 0; j < 4; j++) {
        int row = wc * 64 + j * 16 + lr;
        bfv[j] = *(const bf16x8*)(Bp + ((row * 128 + ks * 64 + g * 16) ^ swz));
      }
      __builtin_amdgcn_s_setprio(1);
#pragma unroll
      for (int i = 0; i < 8; i++)
#pragma unroll
        for (int j = 0; j < 4; j++)
          acc[i][j] = __builtin_amdgcn_mfma_f32_16x16x32_bf16(af[i], bfv[j], acc[i][j], 0, 0, 0);
      __builtin_amdgcn_s_setprio(0);
    }
  }

  const int rq = g * 4;
#pragma unroll
  for (int i = 0; i < 8; i++)
#pragma unroll
    for (int j = 0; j < 4; j++) {
      int mrow = m0 + wr * 128 + i * 16 + rq;
      int ncol = n0 + wc * 64 + j * 16 + lr;
      if (ncol < 4096) {
#pragma unroll
        for (int r = 0; r < 4; r++)
          XQ[(size_t)(mrow + r) * 4096 + ncol] = acc[i][j][r];
      } else if (ncol < 6144) {
#pragma unroll
        for (int r = 0; r < 4; r++)
          XK[(size_t)(mrow + r) * 2048 + ncol - 4096] = acc[i][j][r];
      } else {
#pragma unroll
        for (int r = 0; r < 4; r++)
          Vb[(size_t)(mrow + r) * 2048 + ncol - 6144] = f2bf(acc[i][j][r]);
      }
    }
}

// ---------------- NT GEMM (out-proj): A (MxK) * B (NxK) -> C f32 ----------------
__global__ __launch_bounds__(256) void gemm_nt(const unsigned short* __restrict__ A,
                                               const unsigned short* __restrict__ B,
                                               float* __restrict__ Cf,
                                               int M, int N, int K) {
  __shared__ unsigned short As[128 * 32];
  __shared__ unsigned short Bs[128 * 32];
  const int t = threadIdx.x;
  const int w = t >> 6, l = t & 63;
  const int bid = blockIdx.y * gridDim.x + blockIdx.x;
  const int xcd = bid & 7, ii = bid >> 3;
  const int m0 = (ii & 15) * 128;                       // gridDim.y == 16
  const int n0 = (xcd * (gridDim.x >> 3) + (ii >> 4)) * 128;
  const int wr = (w >> 1) * 64, wc = (w & 1) * 64;
  const int lr = l & 15, lk = (l >> 4) * 8;
  f32x4 acc[4][4] = {};

  const int e0 = t * 8;
  const int ar0 = e0 >> 5, ac0 = e0 & 31;
  const size_t abase = (size_t)(m0 + ar0) * K + ac0;
  const size_t bbase = (size_t)(n0 + ar0) * K + ac0;

  for (int k0 = 0; k0 < K; k0 += 32) {
    gload_lds16(A + abase + k0, As + e0);
    gload_lds16(A + abase + (size_t)64 * K + k0, As + e0 + 2048);
    gload_lds16(B + bbase + k0, Bs + e0);
    gload_lds16(B + bbase + (size_t)64 * K + k0, Bs + e0 + 2048);
    __syncthreads();
    bf16x8 af[4], bfv[4];
#pragma unroll
    for (int i = 0; i < 4; i++)
      af[i] = *(const bf16x8*)(As + (wr + i * 16 + lr) * 32 + lk);
#pragma unroll
    for (int i = 0; i < 4; i++)
      bfv[i] = *(const bf16x8*)(Bs + (wc + i * 16 + lr) * 32 + lk);
#pragma unroll
    for (int i = 0; i < 4; i++)
#pragma unroll
      for (int j = 0; j < 4; j++)
        acc[i][j] = __builtin_amdgcn_mfma_f32_16x16x32_bf16(af[i], bfv[j], acc[i][j], 0, 0, 0);
    __syncthreads();
  }

  const int rq = (l >> 4) * 4;
#pragma unroll
  for (int i = 0; i < 4; i++)
#pragma unroll
    for (int j = 0; j < 4; j++) {
      int mrow = m0 + wr + i * 16 + rq;
      int ncol = n0 + wc + j * 16 + lr;
#pragma unroll
      for (int r = 0; r < 4; r++)
        Cf[(size_t)(mrow + r) * N + ncol] = acc[i][j][r];
    }
}

// ---------------- fused RMSNorm + RoPE; writes head-major [h][s][d] ----------------
__global__ __launch_bounds__(256) void norm_rope(const float* __restrict__ x,
                                                 unsigned short* __restrict__ out,
                                                 const float* __restrict__ w,
                                                 const float* __restrict__ fc,
                                                 const float* __restrict__ fs,
                                                 int heads_per_tok, float scale) {
  __shared__ float sh[256];
  __shared__ float red[4];
  int row = blockIdx.x;
  int t = threadIdx.x;
  float v = x[(size_t)row * 256 + t];
  float ss = v * v;
#pragma unroll
  for (int off = 32; off > 0; off >>= 1) ss += __shfl_down(ss, off);
  if ((t & 63) == 0) red[t >> 6] = ss;
  __syncthreads();
  float tot = red[0] + red[1] + red[2] + red[3];
  float rn = rsqrtf(tot * (1.0f / 256.0f) + EPSV);
  sh[t] = v * rn * (1.0f + w[t]);
  __syncthreads();
  if (t < 128) {
    int s = row / heads_per_tok;
    int h = row - s * heads_per_tok;
    size_t ob = ((size_t)h * S_LEN + s) * HD;
    float xr = sh[t], xi = sh[t + 128];
    float c = fc[(size_t)s * 128 + t], sn = fs[(size_t)s * 128 + t];
    out[ob + t]       = f2bf((xr * c - xi * sn) * scale);
    out[ob + t + 128] = f2bf((xr * sn + xi * c) * scale);
  }
}

// ---------------- flash attention: swapped-QK in-register softmax ----------------
// Q: [NH][S][HD], K: [NKV][S][HD], VT: [NKV][HD][S], O: [S][NH*HD]
__global__ __launch_bounds__(256) void attn(const unsigned short* __restrict__ Q,
                                            const unsigned short* __restrict__ Kc,
                                            const unsigned short* __restrict__ VT,
                                            unsigned short* __restrict__ O) {
  __shared__ unsigned short Ks[2][32 * 256];   // [k][d], rows 512B, swz ((row&7)<<4)
  __shared__ unsigned short Vs[2][256 * 32];   // [d][k], rows 64B, swz (((row>>1)&3)<<4)
  __shared__ unsigned short Ps[4][16][40];     // [wave][q][key]
  const int t = threadIdx.x, w = t >> 6, l = t & 63;
  const int n = blockIdx.x;
  const int kvh = n & 7;
  const int h = kvh * 2 + ((n >> 3) & 1);
  const int qbase = (31 - (n >> 4)) * 64;       // heavy q-tiles dispatched first
  const int lr = l & 15, g = l >> 4, lk = g * 8;
  const int wq0 = qbase + w * 16;
  const int q_own = wq0 + lr;

  const unsigned short* Qh = Q + (size_t)h * S_LEN * HD;
  const char* Khb = (const char*)(Kc + (size_t)kvh * S_LEN * HD);
  const char* Vhb = (const char*)(VT + (size_t)kvh * HD * S_LEN);

  bf16x8 qf[8];
#pragma unroll
  for (int c = 0; c < 8; c++)
    qf[c] = *(const bf16x8*)(Qh + (size_t)(wq0 + lr) * HD + c * 32 + lk);

  f32x4 o_acc[16] = {};
  float m_s = -1e30f, l_s = 0.f;

  auto stage = [&](int kv0, int b) {
#pragma unroll
    for (int i = 0; i < 4; i++) {
      int L = t * 16 + i * 4096;
      int ks = L ^ (((L >> 9) & 7) << 4);
      gload_lds16(Khb + (size_t)kv0 * 512 + ks, (char*)(Ks[b]) + L);
    }
#pragma unroll
    for (int i = 0; i < 4; i++) {
      int L = t * 16 + i * 4096;
      int d = L >> 6;
      int kb = (L & 63) ^ (((d >> 1) & 3) << 4);
      gload_lds16(Vhb + (size_t)d * (S_LEN * 2) + (size_t)kv0 * 2 + kb, (char*)(Vs[b]) + L);
    }
  };

  const int ntB = (qbase + 64) >> 5;
  stage(0, 0);
  __syncthreads();
  int buf = 0;
  for (int tile = 0; tile < ntB; tile++) {
    const int kv0 = tile << 5;
    if (tile + 1 < ntB) stage(kv0 + 32, buf ^ 1);

    if (kv0 <= wq0 + 15) {
      const bool masked = (kv0 + 31 > wq0);     // wave-uniform
      const char* Kb = (const char*)(Ks[buf]);
      const char* Vb = (const char*)(Vs[buf]);

      // S^T: rows=keys, cols=q
      f32x4 sacc[2] = {};
#pragma unroll
      for (int c = 0; c < 8; c++) {
        int a0 = (lr * 512 + c * 64 + g * 16) ^ ((lr & 7) << 4);
        bf16x8 k0f = *(const bf16x8*)(Kb + a0);
        bf16x8 k1f = *(const bf16x8*)(Kb + a0 + 8192);
        sacc[0] = __builtin_amdgcn_mfma_f32_16x16x32_bf16(k0f, qf[c], sacc[0], 0, 0, 0);
        sacc[1] = __builtin_amdgcn_mfma_f32_16x16x32_bf16(k1f, qf[c], sacc[1], 0, 0, 0);
      }

      float sv[8];
#pragma unroll
      for (int nb = 0; nb < 2; nb++)
#pragma unroll
        for (int r = 0; r < 4; r++) {
          float s = sacc[nb][r];
          float ax = fabsf(s) * (2.0f / SOFTCAP);
          float e2 = __expf(-ax);
          s = copysignf((1.f - e2) / (1.f + e2) * SOFTCAP, s);
          if (masked) {
            int kj = kv0 + nb * 16 + 4 * g + r;
            s = (kj <= q_own) ? s : -1e30f;
          }
          sv[nb * 4 + r] = s;
        }

      float mx = fmaxf(fmaxf(fmaxf(sv[0], sv[1]), fmaxf(sv[2], sv[3])),
                       fmaxf(fmaxf(sv[4], sv[5]), fmaxf(sv[6], sv[7])));
      mx = fmaxf(mx, __shfl_xor(mx, 16));
      mx = fmaxf(mx, __shfl_xor(mx, 32));
      float mnew = fmaxf(m_s, mx);
      float corr = __expf(m_s - mnew);

      float ps[8];
      float rs = 0.f;
#pragma unroll
      for (int i = 0; i < 8; i++) {
        ps[i] = __expf(sv[i] - mnew);
        rs += ps[i];
      }
      rs += __shfl_xor(rs, 16);
      rs += __shfl_xor(rs, 32);
      l_s = l_s * corr + rs;
      m_s = mnew;

      if (__any(corr < 1.0f)) {
        f32x4 c4;
#pragma unroll
        for (int r = 0; r < 4; r++) c4[r] = __shfl(corr, 4 * g + r);
#pragma unroll
        for (int fn = 0; fn < 16; fn++) o_acc[fn] *= c4;
      }

      uint2 lo, hi;
      lo.x = (unsigned)f2bf(ps[0]) | ((unsigned)f2bf(ps[1]) << 16);
      lo.y = (unsigned)f2bf(ps[2]) | ((unsigned)f2bf(ps[3]) << 16);
      hi.x = (unsigned)f2bf(ps[4]) | ((unsigned)f2bf(ps[5]) << 16);
      hi.y = (unsigned)f2bf(ps[6]) | ((unsigned)f2bf(ps[7]) << 16);
      *(uint2*)(&Ps[w][lr][4 * g])      = lo;
      *(uint2*)(&Ps[w][lr][16 + 4 * g]) = hi;

      bf16x8 pa = *(const bf16x8*)(&Ps[w][lr][8 * g]);
#pragma unroll
      for (int fn = 0; fn < 16; fn++) {
        int row = fn * 16 + lr;
        int av = (row * 64 + g * 16) ^ (((row >> 1) & 3) << 4);
        bf16x8 vf = *(const bf16x8*)(Vb + av);
        o_acc[fn] = __builtin_amdgcn_mfma_f32_16x16x32_bf16(pa, vf, o_acc[fn], 0, 0, 0);
      }
    }
    __syncthreads();
    buf ^= 1;
  }

  float inv = (l_s > 0.f) ? 1.0f / l_s : 0.f;
  f32x4 inv4;
#pragma unroll
  for (int r = 0; r < 4; r++) inv4[r] = __shfl(inv, 4 * g + r);
#pragma unroll
  for (int fn = 0; fn < 16; fn++) {
    f32x4 ov = o_acc[fn] * inv4;
#pragma unroll
    for (int r = 0; r < 4; r++) {
      int q = wq0 + g * 4 + r;
      O[(size_t)q * 4096 + h * HD + fn * 16 + lr] = f2bf(ov[r]);
    }
  }
}

extern "C" void kernel_launch(void* const* d_in, const int* in_sizes, int n_in,
                              void* d_out, int out_size, void* d_ws, size_t ws_size,
                              hipStream_t stream) {
  const float* hidden = (const float*)d_in[0];
  const float* fc  = (const float*)d_in[1];
  const float* fs  = (const float*)d_in[2];
  const float* wq  = (const float*)d_in[7];
  const float* wk  = (const float*)d_in[8];
  const float* wv  = (const float*)d_in[9];
  const float* wo  = (const float*)d_in[10];
  const float* qnw = (const float*)d_in[11];
  const float* knw = (const float*)d_in[12];
  float* out = (float*)d_out;

  char* ws = (char*)d_ws;
  size_t off = 0;
  auto alloc = [&](size_t bytes) {
    char* p = ws + off;
    off += (bytes + 255) & ~(size_t)255;
    return p;
  };
  unsigned short* Xbf    = (unsigned short*)alloc((size_t)S_LEN * HID * 2);
  unsigned short* WqkvT  = (unsigned short*)alloc((size_t)8192 * HID * 2);
  unsigned short* WoT    = (unsigned short*)alloc((size_t)HID * 4096 * 2);
  float*          XQ32   = (float*)alloc((size_t)S_LEN * 4096 * 4);
  float*          XK32   = (float*)alloc((size_t)S_LEN * 2048 * 4);
  unsigned short* Qbf    = (unsigned short*)alloc((size_t)S_LEN * 4096 * 2);
  unsigned short* Kbf    = (unsigned short*)alloc((size_t)S_LEN * 2048 * 2);
  unsigned short* Vbf    = (unsigned short*)alloc((size_t)S_LEN * 2048 * 2);
  unsigned short* Obf = (unsigned short*)XQ32;   // alias: XQ32 dead after norm_rope Q
  unsigned short* VTb = (unsigned short*)XK32;   // alias: XK32 dead after norm_rope K

  conv_b<<<(S_LEN * HID) / 1024, 256, 0, stream>>>(hidden, Xbf, S_LEN * HID);
  conv_t<<<dim3(4096 / 64, HID / 64), 256, 0, stream>>>(wq, WqkvT, HID, 4096);
  conv_t<<<dim3(2048 / 64, HID / 64), 256, 0, stream>>>(wk, WqkvT + (size_t)4096 * HID, HID, 2048);
  conv_t<<<dim3(2048 / 64, HID / 64), 256, 0, stream>>>(wv, WqkvT + (size_t)6144 * HID, HID, 2048);
  conv_t<<<dim3(HID / 64, 4096 / 64), 256, 0, stream>>>(wo, WoT, 4096, HID);

  gemm_qkv<<<256, 512, 131072, stream>>>(Xbf, WqkvT, XQ32, XK32, Vbf);

  norm_rope<<<S_LEN * NH, 256, 0, stream>>>(XQ32, Qbf, qnw, fc, fs, NH, SCALING);
  norm_rope<<<S_LEN * NKV, 256, 0, stream>>>(XK32, Kbf, knw, fc, fs, NKV, 1.0f);

  tr_bf16<<<dim3(2048 / 32, 2048 / 32), 256, 0, stream>>>(Vbf, VTb, S_LEN, 2048);

  attn<<<512, 256, 0, stream>>>(Qbf, Kbf, VTb, Obf);

  gemm_nt<<<dim3(HID / 128, S_LEN / 128), 256, 0, stream>>>(Obf, WoT, out, S_LEN, HID, 4096);
}